// Round 8
// baseline (184.802 us; speedup 1.0000x reference)
//
#include <hip/hip_runtime.h>
#include <math.h>

// Problem constants
#define Bn 32
#define Sn 16384
#define Kn 64
#define Nn 128

#define NPC 32           // colsum partials per (b,view); prep grid = Bn*2*NPC = 2048
#define NSB 16           // gram blocks per batch -> 512 blocks
#define SPB (Sn/NSB)     // 1024 samples per gram block
#define NCH (SPB/32)     // 32 chunks of 32 samples

typedef __attribute__((ext_vector_type(8))) short bf16x8;          // MFMA frag
typedef __attribute__((ext_vector_type(4))) float f32x4;           // MFMA acc
typedef __attribute__((ext_vector_type(8))) unsigned short u16x8;  // bf16 row piece
typedef __attribute__((ext_vector_type(4))) unsigned short u16x4;

// workspace layout in floats
#define WS_CSPART 0                            // Bn*2*NPC*64 = 131072
#define WS_GRAM   (Bn*2*NPC*64)                // + Bn*3*4096 = 393216
#define WS_LOSS   (WS_GRAM + Bn*3*4096)        // + Bn
#define WS_PART   (WS_LOSS + Bn)               // + Bn*NSB*3*4096
#define WS_PART_SZ ((size_t)Bn*NSB*3*4096)
#define WS_U      (WS_PART + Bn*NSB*3*4096)    // + Bn*Sn*Kn (bf16 u, both views)
#define WS_U_SZ   ((size_t)Bn*Sn*Kn)
#define WS_END_FULL ((size_t)WS_U + WS_U_SZ)
#define WS_END_MED  ((size_t)WS_U)

__device__ __forceinline__ unsigned short f2bf(float f) {
    unsigned int u = __float_as_uint(f);
    u += 0x7FFFu + ((u >> 16) & 1u);
    return (unsigned short)(u >> 16);
}
__device__ __forceinline__ float b2f(unsigned short u) {
    return __uint_as_float((unsigned int)u << 16);
}

// ---------------- Pass 1: q -> u=q^2 (bf16, to ws) + colsum partials ----------------
__global__ __launch_bounds__(256) void k_prep(const float* __restrict__ qi,
                                              const float* __restrict__ qj,
                                              float* __restrict__ ws, int write_u) {
    const int blk   = blockIdx.x;       // 0 .. Bn*2*NPC-1
    const int chunk = blk % NPC;
    const int pair  = blk / NPC;        // b*2 + v
    const int v = pair & 1, b = pair >> 1;
    const float* __restrict__ src = v ? qj : qi;
    unsigned short* __restrict__ udst =
        (unsigned short*)(ws + WS_U) + ((size_t)v * Bn + b) * (size_t)Sn * Kn;
    const int tid = threadIdx.x;
    const int c4 = (tid & 15) * 4;
    const int rg = tid >> 4;            // 0..15
    const int row0 = chunk * (Sn / NPC);   // 512 rows per chunk
    const long bb = (long)b * Sn * Kn;

    f32x4 acc = {0.f, 0.f, 0.f, 0.f};
    #pragma unroll 4
    for (int s = 0; s < 32; ++s) {
        const int row = row0 + s * 16 + rg;
        const float4 q = *(const float4*)(src + bb + (long)row * Kn + c4);
        const f32x4 qq = {q.x * q.x, q.y * q.y, q.z * q.z, q.w * q.w};
        acc += qq;
        if (write_u) {
            u16x4 pk = {f2bf(qq[0]), f2bf(qq[1]), f2bf(qq[2]), f2bf(qq[3])};
            *(u16x4*)(udst + (size_t)row * Kn + c4) = pk;
        }
    }
    __shared__ float red[16 * 64];
    *(f32x4*)&red[rg * 64 + c4] = acc;
    __syncthreads();
    if (tid < 64) {
        float s = 0.f;
        #pragma unroll
        for (int g = 0; g < 16; ++g) s += red[g * 64 + tid];
        ws[WS_CSPART + (pair * NPC + chunk) * 64 + tid] = s;
    }
}

// ---------------- Pass 2: normalize -> bf16 -> MFMA Gram (pipelined) ----------------
// U16=1: stage from bf16 u (134 MB, L3-hot). U16=0: stage from f32 q (fallback).
// LDS lp: [buf][view] p^T chunk as [64 cols][40 bf16]; frag = 1 ds_read_b128.
template<int ATOMIC, int U16>
__global__ __launch_bounds__(256, 4) void k_gram(const float* __restrict__ qi,
                                                 const float* __restrict__ qj,
                                                 float* __restrict__ ws) {
    const int b   = blockIdx.x / NSB;
    const int sb  = blockIdx.x % NSB;
    const int tid = threadIdx.x;
    const int w   = tid >> 6;        // wave 0..3 (owns output rows w*16..+15)
    const int l   = tid & 63;
    const int lc  = tid & 15;        // fragment col lane
    const int c0  = lc * 4;

    __shared__ unsigned short lp[2][2][64 * 40];   // 20.5 KB
    __shared__ float csh[128];                     // [view][64]

    // fold: reduce colsum partials for this batch
    if (tid < 128) {
        const int view = tid >> 6, col = tid & 63;
        float s = 0.f;
        #pragma unroll 8
        for (int p = 0; p < NPC; ++p)
            s += ws[WS_CSPART + ((b * 2 + view) * NPC + p) * 64 + col];
        csh[view * 64 + col] = s;
    }
    __syncthreads();

    f32x4 aII[4], aIJ[4], aJJ[4];
    #pragma unroll
    for (int t = 0; t < 4; ++t) {
        aII[t] = (f32x4){0.f, 0.f, 0.f, 0.f};
        aIJ[t] = (f32x4){0.f, 0.f, 0.f, 0.f};
        aJJ[t] = (f32x4){0.f, 0.f, 0.f, 0.f};
    }

    const long s0g = (long)sb * SPB;

    // ---- F32-path state ----
    const int spf = tid >> 4;            // sample-pair (f32 path)
    float icI[4], icJ[4];
    float4 pfa[2], pfb[2];
    // ---- U16-path state ----
    const int vv  = tid >> 7;            // view handled by this thread
    const int vr  = tid & 127;
    const int spu = vr >> 3;             // sample-pair 0..15
    const int c8  = (vr & 7) * 8;        // 8-col group
    float ic8[8];
    u16x8 pu0, pu1;
    const unsigned short* __restrict__ ubase =
        (const unsigned short*)(ws + WS_U) +
        ((size_t)vv * Bn + b) * (size_t)Sn * Kn;

    if (U16) {
        #pragma unroll
        for (int e = 0; e < 8; ++e) ic8[e] = 1.f / csh[vv * 64 + c8 + e];
    } else {
        #pragma unroll
        for (int e = 0; e < 4; ++e) {
            icI[e] = 1.f / csh[c0 + e];
            icJ[e] = 1.f / csh[64 + c0 + e];
        }
    }

    const long bb = (long)b * Sn * Kn;

    auto issue = [&](int ct) {
        if (U16) {
            const size_t off = (size_t)(s0g + ct * 32 + 2 * spu) * Kn + c8;
            pu0 = *(const u16x8*)(ubase + off);
            pu1 = *(const u16x8*)(ubase + off + Kn);
        } else {
            const long off = bb + (s0g + ct * 32 + 2 * spf) * (long)Kn + c0;
            pfa[0] = *(const float4*)(qi + off);
            pfb[0] = *(const float4*)(qi + off + Kn);
            pfa[1] = *(const float4*)(qj + off);
            pfb[1] = *(const float4*)(qj + off + Kn);
        }
    };
    auto stage = [&](int buf) {
        if (U16) {
            float wa[8], wb[8];
            float ra = 0.f, rb = 0.f;
            #pragma unroll
            for (int e = 0; e < 8; ++e) {
                wa[e] = b2f(pu0[e]) * ic8[e];
                wb[e] = b2f(pu1[e]) * ic8[e];
                ra += wa[e]; rb += wb[e];
            }
            #pragma unroll
            for (int d = 1; d < 8; d <<= 1) {
                ra += __shfl_xor(ra, d);
                rb += __shfl_xor(rb, d);
            }
            const float ia = 1.f / ra, ib = 1.f / rb;
            #pragma unroll
            for (int e = 0; e < 8; ++e) {
                const unsigned int pk = (unsigned int)f2bf(wa[e] * ia)
                                      | ((unsigned int)f2bf(wb[e] * ib) << 16);
                *(unsigned int*)&lp[buf][vv][(c8 + e) * 40 + 2 * spu] = pk;
            }
        } else {
            #pragma unroll
            for (int v = 0; v < 2; ++v) {
                const float* ic = v ? icJ : icI;
                const float4 qa = pfa[v], qb = pfb[v];
                float wa[4] = {qa.x * qa.x * ic[0], qa.y * qa.y * ic[1],
                               qa.z * qa.z * ic[2], qa.w * qa.w * ic[3]};
                float wb[4] = {qb.x * qb.x * ic[0], qb.y * qb.y * ic[1],
                               qb.z * qb.z * ic[2], qb.w * qb.w * ic[3]};
                float ra = wa[0] + wa[1] + wa[2] + wa[3];
                float rb = wb[0] + wb[1] + wb[2] + wb[3];
                #pragma unroll
                for (int d = 1; d < 16; d <<= 1) {
                    ra += __shfl_xor(ra, d);
                    rb += __shfl_xor(rb, d);
                }
                const float ia = 1.f / ra, ib = 1.f / rb;
                #pragma unroll
                for (int cc = 0; cc < 4; ++cc) {
                    const unsigned int pk = (unsigned int)f2bf(wa[cc] * ia)
                                          | ((unsigned int)f2bf(wb[cc] * ib) << 16);
                    *(unsigned int*)&lp[buf][v][(c0 + cc) * 40 + 2 * spf] = pk;
                }
            }
        }
    };

    // prologue: fill buf0, leave chunk-1 loads in flight
    issue(0);
    stage(0);
    issue(1);
    __syncthreads();

    const int sgo = (l >> 4) * 8;
    #pragma unroll 1
    for (int ct = 0; ct < NCH; ++ct) {
        const int cur = ct & 1;
        const bf16x8 ai = *(const bf16x8*)&lp[cur][0][(w * 16 + lc) * 40 + sgo];
        const bf16x8 aj = *(const bf16x8*)&lp[cur][1][(w * 16 + lc) * 40 + sgo];
        #pragma unroll
        for (int nt = 0; nt < 4; ++nt) {
            const bf16x8 fi = *(const bf16x8*)&lp[cur][0][(nt * 16 + lc) * 40 + sgo];
            const bf16x8 fj = *(const bf16x8*)&lp[cur][1][(nt * 16 + lc) * 40 + sgo];
            aII[nt] = __builtin_amdgcn_mfma_f32_16x16x32_bf16(ai, fi, aII[nt], 0, 0, 0);
            aIJ[nt] = __builtin_amdgcn_mfma_f32_16x16x32_bf16(ai, fj, aIJ[nt], 0, 0, 0);
            aJJ[nt] = __builtin_amdgcn_mfma_f32_16x16x32_bf16(aj, fj, aJJ[nt], 0, 0, 0);
        }
        if (ct + 1 < NCH) {
            stage(cur ^ 1);                       // consume chunk ct+1 loads
            if (ct + 2 < NCH) issue(ct + 2);      // refill; in flight across sync
        }
        __syncthreads();
    }

    // epilogue: C/D layout col = l&15, row = (l>>4)*4 + reg
    const int row0 = w * 16 + (l >> 4) * 4;
    if (ATOMIC) {
        float* __restrict__ dst = ws + WS_GRAM + (long)b * 3 * 4096;
        #pragma unroll
        for (int nt = 0; nt < 4; ++nt) {
            #pragma unroll
            for (int r = 0; r < 4; ++r) {
                const int e = (row0 + r) * 64 + nt * 16 + lc;
                atomicAdd(&dst[e],        aII[nt][r]);
                atomicAdd(&dst[4096 + e], aIJ[nt][r]);
                atomicAdd(&dst[8192 + e], aJJ[nt][r]);
            }
        }
    } else {
        float* __restrict__ dst = ws + WS_PART + (long)(b * NSB + sb) * 3 * 4096;
        #pragma unroll
        for (int nt = 0; nt < 4; ++nt) {
            #pragma unroll
            for (int r = 0; r < 4; ++r) {
                const int e = (row0 + r) * 64 + nt * 16 + lc;
                dst[e]        = aII[nt][r];
                dst[4096 + e] = aIJ[nt][r];
                dst[8192 + e] = aJJ[nt][r];
            }
        }
    }
}

// ---------------- Pass 2b: reduce block partials (deterministic) ----------------
__global__ __launch_bounds__(256) void k_gram_reduce(float* __restrict__ ws) {
    const int idx = blockIdx.x * 256 + threadIdx.x;   // < Bn*3*4096
    const int b = idx / (3 * 4096);
    const int e = idx % (3 * 4096);
    float s = 0.f;
    #pragma unroll 8
    for (int p = 0; p < NSB; ++p)
        s += ws[WS_PART + (long)(b * NSB + p) * 3 * 4096 + e];
    ws[WS_GRAM + (long)b * 3 * 4096 + e] = s;
}

// ---------------- Pass 3: per-batch masked-LSE loss ----------------
__device__ __forceinline__ float sim_entry(const float* __restrict__ g, int r, int c) {
    if (r < 64) return (c < 64) ? g[r * 64 + c] : g[4096 + r * 64 + (c - 64)];
    return (c < 64) ? g[4096 + c * 64 + (r - 64)] : g[8192 + (r - 64) * 64 + (c - 64)];
}

__global__ __launch_bounds__(128) void k_loss(const float* __restrict__ temp,
                                              float* __restrict__ ws) {
    const int b = blockIdx.x;
    const int r = threadIdx.x;    // row 0..127
    const float* __restrict__ g = ws + WS_GRAM + (long)b * 3 * 4096;
    const float inv_t = 1.f / temp[0];
    const int p = r ^ 64;

    float m = -1e30f, pos = 0.f;
    for (int c = 0; c < Nn; ++c) {
        if (c == r) continue;
        const float v = sim_entry(g, r, c) * inv_t;
        m = fmaxf(m, v);
        if (c == p) pos = v;
    }
    float sum = 0.f;
    for (int c = 0; c < Nn; ++c) {
        if (c == r) continue;
        const float v = sim_entry(g, r, c) * inv_t;
        sum += expf(v - m);
    }
    const float val = m + logf(sum) - pos;

    __shared__ float red[Nn];
    red[r] = val;
    __syncthreads();
    for (int st = 64; st > 0; st >>= 1) {
        if (r < st) red[r] += red[r + st];
        __syncthreads();
    }
    if (r == 0) ws[WS_LOSS + b] = red[0] / (float)Nn;
}

__global__ void k_final(float* __restrict__ ws, float* __restrict__ out) {
    if (threadIdx.x == 0) {
        float s = 0.f;
        for (int b = 0; b < Bn; ++b) s += ws[WS_LOSS + b];
        out[0] = s / (float)Bn;
    }
}

extern "C" void kernel_launch(void* const* d_in, const int* in_sizes, int n_in,
                              void* d_out, int out_size, void* d_ws, size_t ws_size,
                              hipStream_t stream) {
    const float* qi   = (const float*)d_in[0];
    const float* qj   = (const float*)d_in[1];
    const float* temp = (const float*)d_in[2];
    float* ws  = (float*)d_ws;
    float* out = (float*)d_out;

    const bool full = ws_size >= WS_END_FULL * sizeof(float);
    const bool med  = ws_size >= WS_END_MED * sizeof(float);

    if (full) {
        k_prep<<<Bn * 2 * NPC, 256, 0, stream>>>(qi, qj, ws, 1);
        k_gram<0, 1><<<Bn * NSB, 256, 0, stream>>>(qi, qj, ws);
        k_gram_reduce<<<(Bn * 3 * 4096) / 256, 256, 0, stream>>>(ws);
    } else if (med) {
        k_prep<<<Bn * 2 * NPC, 256, 0, stream>>>(qi, qj, ws, 0);
        k_gram<0, 0><<<Bn * NSB, 256, 0, stream>>>(qi, qj, ws);
        k_gram_reduce<<<(Bn * 3 * 4096) / 256, 256, 0, stream>>>(ws);
    } else {
        k_prep<<<Bn * 2 * NPC, 256, 0, stream>>>(qi, qj, ws, 0);
        hipMemsetAsync(ws + WS_GRAM, 0, (size_t)Bn * 3 * 4096 * sizeof(float), stream);
        k_gram<1, 0><<<Bn * NSB, 256, 0, stream>>>(qi, qj, ws);
    }

    k_loss<<<Bn, 128, 0, stream>>>(temp, ws);
    k_final<<<1, 64, 0, stream>>>(ws, out);
}

// Round 9
// 169.725 us; speedup vs baseline: 1.0888x; 1.0888x over previous
//
#include <hip/hip_runtime.h>
#include <math.h>

// Problem constants
#define Bn 32
#define Sn 16384
#define Kn 64
#define Nn 128

#define P1  8            // colsum chunks per (b,view): grid = Bn*2*P1 = 512 blocks
#define NSB 32           // gram blocks per batch -> 1024 blocks
#define SPB (Sn/NSB)     // 512 samples per gram block
#define NCH (SPB/32)     // 16 chunks of 32 samples

typedef __attribute__((ext_vector_type(8))) short bf16x8;   // MFMA frag
typedef __attribute__((ext_vector_type(4))) float f32x4;

// workspace layout in floats
#define WS_CSPART 0                          // Bn*2*P1*64 = 32768
#define WS_GRAM   (Bn*2*P1*64)               // + Bn*3*4096
#define WS_LOSS   (WS_GRAM + Bn*3*4096)      // + Bn
#define WS_PART   (WS_LOSS + Bn)             // + Bn*NSB*3*4096
#define WS_PART_SZ ((size_t)Bn*NSB*3*4096)

__device__ __forceinline__ unsigned short f2bf(float f) {
    unsigned int u = __float_as_uint(f);
    u += 0x7FFFu + ((u >> 16) & 1u);
    return (unsigned short)(u >> 16);
}

__device__ __forceinline__ void glds16(const float* gp, float* lp) {
    __builtin_amdgcn_global_load_lds(
        (const __attribute__((address_space(1))) void*)gp,
        (__attribute__((address_space(3))) void*)lp, 16, 0, 0);
}

// ---------------- Pass 1: column sums via global_load_lds deep pipeline ----------------
// 512 blocks, 4 independent waves each (no loop barriers). Per wave: two 8-KB
// half-buffers; 8x global_load_lds(16B/lane) per half = 32 rows; steady state
// 16 KB in flight per wave (LDS destinations -> regalloc cannot serialize).
// Counted s_waitcnt vmcnt(8) drains only the older half (T4).
__global__ __launch_bounds__(256) void k_colsum(const float* __restrict__ qi,
                                                const float* __restrict__ qj,
                                                float* __restrict__ ws) {
    const int blk   = blockIdx.x;        // 0 .. Bn*2*P1-1
    const int chunk = blk % P1;
    const int pair  = blk / P1;          // b*2 + v
    const int v = pair & 1, b = pair >> 1;
    const float* __restrict__ src = v ? qj : qi;
    const int tid = threadIdx.x;
    const int w = tid >> 6, l = tid & 63;

    __shared__ float stg[4][2][2048];    // 64 KB: [wave][half][8KB buffer]
    __shared__ float red[4][4][64];      // cross-wave reduction

    const float* __restrict__ gbase =
        src + (long)b * Sn * Kn + (long)(chunk * (Sn / P1)) * Kn + l * 4;
    // wave w owns rows [w*512, +512) of this block's 2048-row chunk; 16 halves x 32 rows

    auto issueHalf = [&](int h, int buf) {
        const float* gp = gbase + (long)(w * 512 + h * 32) * Kn;
        float* lp = &stg[w][buf][0];
        #pragma unroll
        for (int k = 0; k < 8; ++k)              // 1KB each: 4 rows x 64 cols
            glds16(gp + (long)k * 4 * Kn, lp + k * 256);
    };

    f32x4 acc = {0.f, 0.f, 0.f, 0.f};

    issueHalf(0, 0);
    issueHalf(1, 1);
    #pragma unroll 1
    for (int h = 0; h < 16; ++h) {
        const int buf = h & 1;
        if (h + 1 < 16) asm volatile("s_waitcnt vmcnt(8)" ::: "memory");
        else            asm volatile("s_waitcnt vmcnt(0)" ::: "memory");
        __builtin_amdgcn_sched_barrier(0);
        // lane l reads back its own 16B: floats l*4..+3 of each 1KB sub-buffer
        #pragma unroll
        for (int k = 0; k < 8; ++k)
            acc += *(const f32x4*)&stg[w][buf][k * 256 + l * 4];
        asm volatile("s_waitcnt lgkmcnt(0)" ::: "memory");   // reads done before overwrite
        __builtin_amdgcn_sched_barrier(0);
        if (h + 2 < 16) issueHalf(h + 2, buf);
    }

    // lane l holds cols (l&15)*4..+3 over rows == (l>>4) mod 4
    *(f32x4*)&red[w][l >> 4][(l & 15) * 4] = acc;
    __syncthreads();
    if (tid < 64) {
        float s = 0.f;
        #pragma unroll
        for (int g = 0; g < 16; ++g) s += red[g >> 2][g & 3][tid];
        ws[WS_CSPART + (pair * P1 + chunk) * 64 + tid] = s;
    }
}

// ---------------- Pass 2: normalize -> bf16 -> MFMA Gram (pipelined) ----------------
// Prologue folds the colsum-partial reduction (P1=8 per view).
// LDS: [buf][view] p^T chunk as [64 cols][40 bf16]; frag = 1 ds_read_b128.
template<int ATOMIC>
__global__ __launch_bounds__(256, 4) void k_gram(const float* __restrict__ qi,
                                                 const float* __restrict__ qj,
                                                 float* __restrict__ ws) {
    const int b   = blockIdx.x / NSB;
    const int sb  = blockIdx.x % NSB;
    const int tid = threadIdx.x;
    const int w   = tid >> 6;        // wave 0..3 (owns output rows w*16..+15)
    const int l   = tid & 63;
    const int lc  = tid & 15;        // fragment col lane
    const int sp  = tid >> 4;        // sample-pair 0..15
    const int c0  = lc * 4;

    __shared__ unsigned short lp[2][2][64 * 40];   // 20.5 KB
    __shared__ float csh[128];                     // [view][64]

    if (tid < 128) {
        const int view = tid >> 6, col = tid & 63;
        float s = 0.f;
        #pragma unroll
        for (int p = 0; p < P1; ++p)
            s += ws[WS_CSPART + ((b * 2 + view) * P1 + p) * 64 + col];
        csh[view * 64 + col] = s;
    }
    __syncthreads();

    const float icI[4] = {1.f / csh[c0], 1.f / csh[c0 + 1],
                          1.f / csh[c0 + 2], 1.f / csh[c0 + 3]};
    const float icJ[4] = {1.f / csh[64 + c0], 1.f / csh[64 + c0 + 1],
                          1.f / csh[64 + c0 + 2], 1.f / csh[64 + c0 + 3]};

    f32x4 aII[4], aIJ[4], aJJ[4];
    #pragma unroll
    for (int t = 0; t < 4; ++t) {
        aII[t] = (f32x4){0.f, 0.f, 0.f, 0.f};
        aIJ[t] = (f32x4){0.f, 0.f, 0.f, 0.f};
        aJJ[t] = (f32x4){0.f, 0.f, 0.f, 0.f};
    }

    const long bb  = (long)b * Sn * Kn;
    const long s0g = (long)sb * SPB;

    float4 pfa[2], pfb[2];

    auto issue = [&](int ct) {
        const long off = bb + (s0g + ct * 32 + 2 * sp) * (long)Kn + c0;
        pfa[0] = *(const float4*)(qi + off);
        pfb[0] = *(const float4*)(qi + off + Kn);
        pfa[1] = *(const float4*)(qj + off);
        pfb[1] = *(const float4*)(qj + off + Kn);
    };
    auto stage = [&](int buf) {
        #pragma unroll
        for (int v = 0; v < 2; ++v) {
            const float* ic = v ? icJ : icI;
            const float4 qa = pfa[v], qb = pfb[v];
            float wa[4] = {qa.x * qa.x * ic[0], qa.y * qa.y * ic[1],
                           qa.z * qa.z * ic[2], qa.w * qa.w * ic[3]};
            float wb[4] = {qb.x * qb.x * ic[0], qb.y * qb.y * ic[1],
                           qb.z * qb.z * ic[2], qb.w * qb.w * ic[3]};
            float ra = wa[0] + wa[1] + wa[2] + wa[3];
            float rb = wb[0] + wb[1] + wb[2] + wb[3];
            #pragma unroll
            for (int d = 1; d < 16; d <<= 1) {
                ra += __shfl_xor(ra, d);
                rb += __shfl_xor(rb, d);
            }
            const float ia = 1.f / ra, ib = 1.f / rb;
            #pragma unroll
            for (int cc = 0; cc < 4; ++cc) {
                const unsigned int pk = (unsigned int)f2bf(wa[cc] * ia)
                                      | ((unsigned int)f2bf(wb[cc] * ib) << 16);
                *(unsigned int*)&lp[buf][v][(c0 + cc) * 40 + 2 * sp] = pk;
            }
        }
    };

    issue(0);
    stage(0);
    issue(1);
    __syncthreads();

    const int sgo = (l >> 4) * 8;
    #pragma unroll 1
    for (int ct = 0; ct < NCH; ++ct) {
        const int cur = ct & 1;
        const bf16x8 ai = *(const bf16x8*)&lp[cur][0][(w * 16 + lc) * 40 + sgo];
        const bf16x8 aj = *(const bf16x8*)&lp[cur][1][(w * 16 + lc) * 40 + sgo];
        #pragma unroll
        for (int nt = 0; nt < 4; ++nt) {
            const bf16x8 fi = *(const bf16x8*)&lp[cur][0][(nt * 16 + lc) * 40 + sgo];
            const bf16x8 fj = *(const bf16x8*)&lp[cur][1][(nt * 16 + lc) * 40 + sgo];
            aII[nt] = __builtin_amdgcn_mfma_f32_16x16x32_bf16(ai, fi, aII[nt], 0, 0, 0);
            aIJ[nt] = __builtin_amdgcn_mfma_f32_16x16x32_bf16(ai, fj, aIJ[nt], 0, 0, 0);
            aJJ[nt] = __builtin_amdgcn_mfma_f32_16x16x32_bf16(aj, fj, aJJ[nt], 0, 0, 0);
        }
        if (ct + 1 < NCH) {
            stage(cur ^ 1);
            if (ct + 2 < NCH) issue(ct + 2);
        }
        __syncthreads();
    }

    const int row0 = w * 16 + (l >> 4) * 4;
    if (ATOMIC) {
        float* __restrict__ dst = ws + WS_GRAM + (long)b * 3 * 4096;
        #pragma unroll
        for (int nt = 0; nt < 4; ++nt) {
            #pragma unroll
            for (int r = 0; r < 4; ++r) {
                const int e = (row0 + r) * 64 + nt * 16 + lc;
                atomicAdd(&dst[e],        aII[nt][r]);
                atomicAdd(&dst[4096 + e], aIJ[nt][r]);
                atomicAdd(&dst[8192 + e], aJJ[nt][r]);
            }
        }
    } else {
        float* __restrict__ dst = ws + WS_PART + (long)(b * NSB + sb) * 3 * 4096;
        #pragma unroll
        for (int nt = 0; nt < 4; ++nt) {
            #pragma unroll
            for (int r = 0; r < 4; ++r) {
                const int e = (row0 + r) * 64 + nt * 16 + lc;
                dst[e]        = aII[nt][r];
                dst[4096 + e] = aIJ[nt][r];
                dst[8192 + e] = aJJ[nt][r];
            }
        }
    }
}

// ---------------- Pass 2b: reduce block partials (deterministic) ----------------
__global__ __launch_bounds__(256) void k_gram_reduce(float* __restrict__ ws) {
    const int idx = blockIdx.x * 256 + threadIdx.x;   // < Bn*3*4096
    const int b = idx / (3 * 4096);
    const int e = idx % (3 * 4096);
    float s = 0.f;
    #pragma unroll 8
    for (int p = 0; p < NSB; ++p)
        s += ws[WS_PART + (long)(b * NSB + p) * 3 * 4096 + e];
    ws[WS_GRAM + (long)b * 3 * 4096 + e] = s;
}

// ---------------- Pass 3: per-batch masked-LSE loss ----------------
__device__ __forceinline__ float sim_entry(const float* __restrict__ g, int r, int c) {
    if (r < 64) return (c < 64) ? g[r * 64 + c] : g[4096 + r * 64 + (c - 64)];
    return (c < 64) ? g[4096 + c * 64 + (r - 64)] : g[8192 + (r - 64) * 64 + (c - 64)];
}

__global__ __launch_bounds__(128) void k_loss(const float* __restrict__ temp,
                                              float* __restrict__ ws) {
    const int b = blockIdx.x;
    const int r = threadIdx.x;
    const float* __restrict__ g = ws + WS_GRAM + (long)b * 3 * 4096;
    const float inv_t = 1.f / temp[0];
    const int p = r ^ 64;

    float m = -1e30f, pos = 0.f;
    for (int c = 0; c < Nn; ++c) {
        if (c == r) continue;
        const float v = sim_entry(g, r, c) * inv_t;
        m = fmaxf(m, v);
        if (c == p) pos = v;
    }
    float sum = 0.f;
    for (int c = 0; c < Nn; ++c) {
        if (c == r) continue;
        const float v = sim_entry(g, r, c) * inv_t;
        sum += expf(v - m);
    }
    const float val = m + logf(sum) - pos;

    __shared__ float red[Nn];
    red[r] = val;
    __syncthreads();
    for (int st = 64; st > 0; st >>= 1) {
        if (r < st) red[r] += red[r + st];
        __syncthreads();
    }
    if (r == 0) ws[WS_LOSS + b] = red[0] / (float)Nn;
}

__global__ void k_final(float* __restrict__ ws, float* __restrict__ out) {
    if (threadIdx.x == 0) {
        float s = 0.f;
        for (int b = 0; b < Bn; ++b) s += ws[WS_LOSS + b];
        out[0] = s / (float)Bn;
    }
}

extern "C" void kernel_launch(void* const* d_in, const int* in_sizes, int n_in,
                              void* d_out, int out_size, void* d_ws, size_t ws_size,
                              hipStream_t stream) {
    const float* qi   = (const float*)d_in[0];
    const float* qj   = (const float*)d_in[1];
    const float* temp = (const float*)d_in[2];
    float* ws  = (float*)d_ws;
    float* out = (float*)d_out;

    const size_t need_f = (size_t)WS_PART + WS_PART_SZ;
    const bool partial = ws_size >= need_f * sizeof(float);

    k_colsum<<<Bn * 2 * P1, 256, 0, stream>>>(qi, qj, ws);

    if (partial) {
        k_gram<0><<<Bn * NSB, 256, 0, stream>>>(qi, qj, ws);
        k_gram_reduce<<<(Bn * 3 * 4096) / 256, 256, 0, stream>>>(ws);
    } else {
        hipMemsetAsync(ws + WS_GRAM, 0, (size_t)Bn * 3 * 4096 * sizeof(float), stream);
        k_gram<1><<<Bn * NSB, 256, 0, stream>>>(qi, qj, ws);
    }

    k_loss<<<Bn, 128, 0, stream>>>(temp, ws);
    k_final<<<1, 64, 0, stream>>>(ws, out);
}

// Round 10
// 165.475 us; speedup vs baseline: 1.1168x; 1.0257x over previous
//
#include <hip/hip_runtime.h>
#include <math.h>

// Problem constants
#define Bn 32
#define Sn 16384
#define Kn 64
#define Nn 128

#define NSB 32           // blocks per batch (both passes) -> 1024 blocks
#define SPB (Sn/NSB)     // 512 samples per block
#define NCH (SPB/32)     // 16 chunks of 32 samples

typedef __attribute__((ext_vector_type(8))) short bf16x8;   // MFMA frag
typedef __attribute__((ext_vector_type(4))) float f32x4;

// workspace layout in floats
#define WS_CSPART 0                          // Bn*2*NSB*64 = 131072
#define WS_GRAM   (Bn*2*NSB*64)              // + Bn*3*4096
#define WS_LOSS   (WS_GRAM + Bn*3*4096)      // + Bn
#define WS_PART   (WS_LOSS + Bn)             // + Bn*NSB*3*4096
#define WS_PART_SZ ((size_t)Bn*NSB*3*4096)

__device__ __forceinline__ unsigned short f2bf(float f) {
    unsigned int u = __float_as_uint(f);
    u += 0x7FFFu + ((u >> 16) & 1u);
    return (unsigned short)(u >> 16);
}

// ---------------- Pass 1: colsum via MFMA (gram-shaped pipeline) ----------------
// Empirical rule from rounds 2-9: this load pattern sustains ~5 TB/s only when
// staged through LDS with MFMA work between loads. So compute colsum WITH MFMA:
// D = A.B with A = all-ones -> every D row = 32-sample column sum. Exact clone
// of k_gram's schedule; stage squares q (no normalize); epilogue writes D row 0.
__global__ __launch_bounds__(256, 4) void k_colsum(const float* __restrict__ qi,
                                                   const float* __restrict__ qj,
                                                   float* __restrict__ ws) {
    const int b   = blockIdx.x / NSB;
    const int sb  = blockIdx.x % NSB;
    const int tid = threadIdx.x;
    const int w   = tid >> 6;
    const int l   = tid & 63;
    const int lc  = tid & 15;
    const int sp  = tid >> 4;        // sample-pair 0..15
    const int c0  = lc * 4;

    __shared__ unsigned short lp[2][2][64 * 40];   // [buf][view][col][40], 20.5 KB

    f32x4 cs[2][4];
    #pragma unroll
    for (int v = 0; v < 2; ++v)
        #pragma unroll
        for (int nt = 0; nt < 4; ++nt) cs[v][nt] = (f32x4){0.f, 0.f, 0.f, 0.f};

    const long bb  = (long)b * Sn * Kn;
    const long s0g = (long)sb * SPB;

    float4 pfa[2], pfb[2];
    auto issue = [&](int ct) {
        const long off = bb + (s0g + ct * 32 + 2 * sp) * (long)Kn + c0;
        pfa[0] = *(const float4*)(qi + off);
        pfb[0] = *(const float4*)(qi + off + Kn);
        pfa[1] = *(const float4*)(qj + off);
        pfb[1] = *(const float4*)(qj + off + Kn);
    };
    auto stage = [&](int buf) {
        #pragma unroll
        for (int v = 0; v < 2; ++v) {
            const float4 qa = pfa[v], qb = pfb[v];
            const float ta[4] = {qa.x * qa.x, qa.y * qa.y, qa.z * qa.z, qa.w * qa.w};
            const float tb[4] = {qb.x * qb.x, qb.y * qb.y, qb.z * qb.z, qb.w * qb.w};
            #pragma unroll
            for (int cc = 0; cc < 4; ++cc) {
                const unsigned int pk = (unsigned int)f2bf(ta[cc])
                                      | ((unsigned int)f2bf(tb[cc]) << 16);
                *(unsigned int*)&lp[buf][v][(c0 + cc) * 40 + 2 * sp] = pk;
            }
        }
    };

    bf16x8 ones;
    #pragma unroll
    for (int e = 0; e < 8; ++e) ones[e] = (short)0x3F80;   // bf16 1.0

    issue(0);
    stage(0);
    issue(1);
    __syncthreads();

    const int sgo = (l >> 4) * 8;
    #pragma unroll 1
    for (int ct = 0; ct < NCH; ++ct) {
        const int cur = ct & 1;
        #pragma unroll
        for (int nt = 0; nt < 4; ++nt) {
            const bf16x8 fi = *(const bf16x8*)&lp[cur][0][(nt * 16 + lc) * 40 + sgo];
            const bf16x8 fj = *(const bf16x8*)&lp[cur][1][(nt * 16 + lc) * 40 + sgo];
            cs[0][nt] = __builtin_amdgcn_mfma_f32_16x16x32_bf16(ones, fi, cs[0][nt], 0, 0, 0);
            cs[1][nt] = __builtin_amdgcn_mfma_f32_16x16x32_bf16(ones, fj, cs[1][nt], 0, 0, 0);
        }
        if (ct + 1 < NCH) {
            stage(cur ^ 1);
            if (ct + 2 < NCH) issue(ct + 2);
        }
        __syncthreads();
    }

    // D row 0 (reg 0, lanes 0..15) = colsum of this block's 512 samples
    if (w == 0 && l < 16) {
        #pragma unroll
        for (int v = 0; v < 2; ++v)
            #pragma unroll
            for (int nt = 0; nt < 4; ++nt)
                ws[WS_CSPART + ((b * 2 + v) * NSB + sb) * 64 + nt * 16 + l] = cs[v][nt][0];
    }
}

// ---------------- Pass 2: normalize -> bf16 -> MFMA Gram (pipelined) ----------------
template<int ATOMIC>
__global__ __launch_bounds__(256, 4) void k_gram(const float* __restrict__ qi,
                                                 const float* __restrict__ qj,
                                                 float* __restrict__ ws) {
    const int b   = blockIdx.x / NSB;
    const int sb  = blockIdx.x % NSB;
    const int tid = threadIdx.x;
    const int w   = tid >> 6;
    const int l   = tid & 63;
    const int lc  = tid & 15;
    const int sp  = tid >> 4;
    const int c0  = lc * 4;

    __shared__ unsigned short lp[2][2][64 * 40];
    __shared__ float csh[128];

    if (tid < 128) {
        const int view = tid >> 6, col = tid & 63;
        float s = 0.f;
        #pragma unroll 8
        for (int p = 0; p < NSB; ++p)
            s += ws[WS_CSPART + ((b * 2 + view) * NSB + p) * 64 + col];
        csh[view * 64 + col] = s;
    }
    __syncthreads();

    const float icI[4] = {1.f / csh[c0], 1.f / csh[c0 + 1],
                          1.f / csh[c0 + 2], 1.f / csh[c0 + 3]};
    const float icJ[4] = {1.f / csh[64 + c0], 1.f / csh[64 + c0 + 1],
                          1.f / csh[64 + c0 + 2], 1.f / csh[64 + c0 + 3]};

    f32x4 aII[4], aIJ[4], aJJ[4];
    #pragma unroll
    for (int t = 0; t < 4; ++t) {
        aII[t] = (f32x4){0.f, 0.f, 0.f, 0.f};
        aIJ[t] = (f32x4){0.f, 0.f, 0.f, 0.f};
        aJJ[t] = (f32x4){0.f, 0.f, 0.f, 0.f};
    }

    const long bb  = (long)b * Sn * Kn;
    const long s0g = (long)sb * SPB;

    float4 pfa[2], pfb[2];
    auto issue = [&](int ct) {
        const long off = bb + (s0g + ct * 32 + 2 * sp) * (long)Kn + c0;
        pfa[0] = *(const float4*)(qi + off);
        pfb[0] = *(const float4*)(qi + off + Kn);
        pfa[1] = *(const float4*)(qj + off);
        pfb[1] = *(const float4*)(qj + off + Kn);
    };
    auto stage = [&](int buf) {
        #pragma unroll
        for (int v = 0; v < 2; ++v) {
            const float* ic = v ? icJ : icI;
            const float4 qa = pfa[v], qb = pfb[v];
            float wa[4] = {qa.x * qa.x * ic[0], qa.y * qa.y * ic[1],
                           qa.z * qa.z * ic[2], qa.w * qa.w * ic[3]};
            float wb[4] = {qb.x * qb.x * ic[0], qb.y * qb.y * ic[1],
                           qb.z * qb.z * ic[2], qb.w * qb.w * ic[3]};
            float ra = wa[0] + wa[1] + wa[2] + wa[3];
            float rb = wb[0] + wb[1] + wb[2] + wb[3];
            #pragma unroll
            for (int d = 1; d < 16; d <<= 1) {
                ra += __shfl_xor(ra, d);
                rb += __shfl_xor(rb, d);
            }
            const float ia = 1.f / ra, ib = 1.f / rb;
            #pragma unroll
            for (int cc = 0; cc < 4; ++cc) {
                const unsigned int pk = (unsigned int)f2bf(wa[cc] * ia)
                                      | ((unsigned int)f2bf(wb[cc] * ib) << 16);
                *(unsigned int*)&lp[buf][v][(c0 + cc) * 40 + 2 * sp] = pk;
            }
        }
    };

    issue(0);
    stage(0);
    issue(1);
    __syncthreads();

    const int sgo = (l >> 4) * 8;
    #pragma unroll 1
    for (int ct = 0; ct < NCH; ++ct) {
        const int cur = ct & 1;
        const bf16x8 ai = *(const bf16x8*)&lp[cur][0][(w * 16 + lc) * 40 + sgo];
        const bf16x8 aj = *(const bf16x8*)&lp[cur][1][(w * 16 + lc) * 40 + sgo];
        #pragma unroll
        for (int nt = 0; nt < 4; ++nt) {
            const bf16x8 fi = *(const bf16x8*)&lp[cur][0][(nt * 16 + lc) * 40 + sgo];
            const bf16x8 fj = *(const bf16x8*)&lp[cur][1][(nt * 16 + lc) * 40 + sgo];
            aII[nt] = __builtin_amdgcn_mfma_f32_16x16x32_bf16(ai, fi, aII[nt], 0, 0, 0);
            aIJ[nt] = __builtin_amdgcn_mfma_f32_16x16x32_bf16(ai, fj, aIJ[nt], 0, 0, 0);
            aJJ[nt] = __builtin_amdgcn_mfma_f32_16x16x32_bf16(aj, fj, aJJ[nt], 0, 0, 0);
        }
        if (ct + 1 < NCH) {
            stage(cur ^ 1);
            if (ct + 2 < NCH) issue(ct + 2);
        }
        __syncthreads();
    }

    const int row0 = w * 16 + (l >> 4) * 4;
    if (ATOMIC) {
        float* __restrict__ dst = ws + WS_GRAM + (long)b * 3 * 4096;
        #pragma unroll
        for (int nt = 0; nt < 4; ++nt) {
            #pragma unroll
            for (int r = 0; r < 4; ++r) {
                const int e = (row0 + r) * 64 + nt * 16 + lc;
                atomicAdd(&dst[e],        aII[nt][r]);
                atomicAdd(&dst[4096 + e], aIJ[nt][r]);
                atomicAdd(&dst[8192 + e], aJJ[nt][r]);
            }
        }
    } else {
        float* __restrict__ dst = ws + WS_PART + (long)(b * NSB + sb) * 3 * 4096;
        #pragma unroll
        for (int nt = 0; nt < 4; ++nt) {
            #pragma unroll
            for (int r = 0; r < 4; ++r) {
                const int e = (row0 + r) * 64 + nt * 16 + lc;
                dst[e]        = aII[nt][r];
                dst[4096 + e] = aIJ[nt][r];
                dst[8192 + e] = aJJ[nt][r];
            }
        }
    }
}

// ---------------- Pass 2b: reduce block partials (deterministic) ----------------
__global__ __launch_bounds__(256) void k_gram_reduce(float* __restrict__ ws) {
    const int idx = blockIdx.x * 256 + threadIdx.x;
    const int b = idx / (3 * 4096);
    const int e = idx % (3 * 4096);
    float s = 0.f;
    #pragma unroll 8
    for (int p = 0; p < NSB; ++p)
        s += ws[WS_PART + (long)(b * NSB + p) * 3 * 4096 + e];
    ws[WS_GRAM + (long)b * 3 * 4096 + e] = s;
}

// ---------------- Pass 3: per-batch masked-LSE loss ----------------
__device__ __forceinline__ float sim_entry(const float* __restrict__ g, int r, int c) {
    if (r < 64) return (c < 64) ? g[r * 64 + c] : g[4096 + r * 64 + (c - 64)];
    return (c < 64) ? g[4096 + c * 64 + (r - 64)] : g[8192 + (r - 64) * 64 + (c - 64)];
}

__global__ __launch_bounds__(128) void k_loss(const float* __restrict__ temp,
                                              float* __restrict__ ws) {
    const int b = blockIdx.x;
    const int r = threadIdx.x;
    const float* __restrict__ g = ws + WS_GRAM + (long)b * 3 * 4096;
    const float inv_t = 1.f / temp[0];
    const int p = r ^ 64;

    float m = -1e30f, pos = 0.f;
    for (int c = 0; c < Nn; ++c) {
        if (c == r) continue;
        const float v = sim_entry(g, r, c) * inv_t;
        m = fmaxf(m, v);
        if (c == p) pos = v;
    }
    float sum = 0.f;
    for (int c = 0; c < Nn; ++c) {
        if (c == r) continue;
        const float v = sim_entry(g, r, c) * inv_t;
        sum += expf(v - m);
    }
    const float val = m + logf(sum) - pos;

    __shared__ float red[Nn];
    red[r] = val;
    __syncthreads();
    for (int st = 64; st > 0; st >>= 1) {
        if (r < st) red[r] += red[r + st];
        __syncthreads();
    }
    if (r == 0) ws[WS_LOSS + b] = red[0] / (float)Nn;
}

__global__ void k_final(float* __restrict__ ws, float* __restrict__ out) {
    if (threadIdx.x == 0) {
        float s = 0.f;
        for (int b = 0; b < Bn; ++b) s += ws[WS_LOSS + b];
        out[0] = s / (float)Bn;
    }
}

extern "C" void kernel_launch(void* const* d_in, const int* in_sizes, int n_in,
                              void* d_out, int out_size, void* d_ws, size_t ws_size,
                              hipStream_t stream) {
    const float* qi   = (const float*)d_in[0];
    const float* qj   = (const float*)d_in[1];
    const float* temp = (const float*)d_in[2];
    float* ws  = (float*)d_ws;
    float* out = (float*)d_out;

    const size_t need_f = (size_t)WS_PART + WS_PART_SZ;
    const bool partial = ws_size >= need_f * sizeof(float);

    k_colsum<<<Bn * NSB, 256, 0, stream>>>(qi, qj, ws);

    if (partial) {
        k_gram<0><<<Bn * NSB, 256, 0, stream>>>(qi, qj, ws);
        k_gram_reduce<<<(Bn * 3 * 4096) / 256, 256, 0, stream>>>(ws);
    } else {
        hipMemsetAsync(ws + WS_GRAM, 0, (size_t)Bn * 3 * 4096 * sizeof(float), stream);
        k_gram<1><<<Bn * NSB, 256, 0, stream>>>(qi, qj, ws);
    }

    k_loss<<<Bn, 128, 0, stream>>>(temp, ws);
    k_final<<<1, 64, 0, stream>>>(ws, out);
}